// Round 1
// baseline (703.515 us; speedup 1.0000x reference)
//
#include <hip/hip_runtime.h>
#include <math.h>

#define BN_EPS 1e-3f
#define GEMV_ROWS 128
#define GEMV_COLS 1024

// Kernel A: one 64-lane wave per node. Lanes gather K=64 neighbor values
// (adj row is a coalesced 256B read; x is 32KB -> L1/L2 resident),
// shuffle-reduce across the wave, lane 0 applies BatchNorm to both halves
// of h = concat([x, x + ngh_sum]) and writes h_bn[2N].
__global__ void agg_bn_kernel(const float* __restrict__ x,
                              const int* __restrict__ adj,
                              const float* __restrict__ bn_gamma,
                              const float* __restrict__ bn_beta,
                              const float* __restrict__ bn_mean,
                              const float* __restrict__ bn_var,
                              float* __restrict__ h_bn,
                              int N, int K)
{
    int gid  = blockIdx.x * blockDim.x + threadIdx.x;
    int node = gid >> 6;
    int lane = gid & 63;
    if (node >= N) return;

    float s = 0.0f;
    for (int k = lane; k < K; k += 64) {
        int nb = adj[(size_t)node * K + k];
        s += x[nb];
    }
#pragma unroll
    for (int off = 32; off > 0; off >>= 1)
        s += __shfl_down(s, off, 64);

    if (lane == 0) {
        float xi  = x[node];
        float agg = xi + s;
        {
            float sc = rsqrtf(bn_var[node] + BN_EPS) * bn_gamma[node];
            h_bn[node] = (xi - bn_mean[node]) * sc + bn_beta[node];
        }
        {
            int j = N + node;
            float sc = rsqrtf(bn_var[j] + BN_EPS) * bn_gamma[j];
            h_bn[j] = (agg - bn_mean[j]) * sc + bn_beta[j];
        }
    }
}

// Kernel B: out_partial[j] += sum_{i in row chunk} h[i] * W[i][j].
// Grid: (N/GEMV_COLS col-blocks, 2N/GEMV_ROWS row-chunks) = (8,128) = 1024 blocks.
// Each thread owns 4 consecutive columns (float4 loads, 16B/lane coalesced),
// h chunk staged in LDS, one atomicAdd per column per block.
__global__ void gemv_partial_kernel(const float* __restrict__ h,
                                    const float* __restrict__ W,
                                    float* __restrict__ acc,
                                    int N)
{
    __shared__ float hs[GEMV_ROWS];
    int row0 = blockIdx.y * GEMV_ROWS;
    for (int i = threadIdx.x; i < GEMV_ROWS; i += blockDim.x)
        hs[i] = h[row0 + i];
    __syncthreads();

    int col = blockIdx.x * GEMV_COLS + threadIdx.x * 4;
    const float* Wp = W + (size_t)row0 * N + col;

    float ax = 0.0f, ay = 0.0f, az = 0.0f, aw = 0.0f;
#pragma unroll 4
    for (int r = 0; r < GEMV_ROWS; ++r) {
        float4 w = *(const float4*)(Wp + (size_t)r * N);
        float hv = hs[r];
        ax = fmaf(hv, w.x, ax);
        ay = fmaf(hv, w.y, ay);
        az = fmaf(hv, w.z, az);
        aw = fmaf(hv, w.w, aw);
    }
    atomicAdd(&acc[col + 0], ax);
    atomicAdd(&acc[col + 1], ay);
    atomicAdd(&acc[col + 2], az);
    atomicAdd(&acc[col + 3], aw);
}

// Kernel C: out[j] = gelu(acc[j] + b[j]), exact erf form per tf.nn.gelu.
__global__ void bias_gelu_kernel(const float* __restrict__ acc,
                                 const float* __restrict__ b,
                                 float* __restrict__ out, int N)
{
    int j = blockIdx.x * blockDim.x + threadIdx.x;
    if (j < N) {
        float v = acc[j] + b[j];
        out[j] = 0.5f * v * (1.0f + erff(v * 0.70710678118654752f));
    }
}

extern "C" void kernel_launch(void* const* d_in, const int* in_sizes, int n_in,
                              void* d_out, int out_size, void* d_ws, size_t ws_size,
                              hipStream_t stream)
{
    const float* x   = (const float*)d_in[0];   // [1, N]
    const int*   adj = (const int*)d_in[1];     // [N, K] (integer -> int32 per harness)
    // d_in[2] = edge_weights: unused by the reference
    const float* W   = (const float*)d_in[3];   // [2N, N]
    const float* b   = (const float*)d_in[4];   // [N]
    const float* g   = (const float*)d_in[5];   // bn_gamma [2N]
    const float* be  = (const float*)d_in[6];   // bn_beta  [2N]
    const float* mn  = (const float*)d_in[7];   // bn_mean  [2N]
    const float* vr  = (const float*)d_in[8];   // bn_var   [2N]
    float* out = (float*)d_out;

    int N = in_sizes[0];       // 8192
    int K = in_sizes[1] / N;   // 64

    // Workspace layout: acc [N] floats | h_bn [2N] floats  (96 KiB total)
    float* acc  = (float*)d_ws;
    float* h_bn = acc + N;

    // acc must start at zero every call (ws is re-poisoned to 0xAA).
    hipMemsetAsync(acc, 0, (size_t)N * sizeof(float), stream);

    {
        // one 64-lane wave per node
        long long total_threads = (long long)N * 64;
        int threads = 256;
        int blocks = (int)((total_threads + threads - 1) / threads);
        agg_bn_kernel<<<blocks, threads, 0, stream>>>(x, adj, g, be, mn, vr, h_bn, N, K);
    }
    {
        dim3 grid(N / GEMV_COLS, (2 * N) / GEMV_ROWS);
        gemv_partial_kernel<<<grid, 256, 0, stream>>>(h_bn, W, acc, N);
    }
    bias_gelu_kernel<<<(N + 255) / 256, 256, 0, stream>>>(acc, b, out, N);
}